// Round 4
// baseline (311.826 us; speedup 1.0000x reference)
//
#include <hip/hip_runtime.h>
#include <hip/hip_fp16.h>
#include <math.h>

// Problem: B=2, S=2048, D=1024, H=16, HD=64, causal attention + RoPE.
// ALL inputs fp32 (reference dtypes), output fp32.
#define B_  2
#define S_  2048
#define D_  1024
#define H_  16
#define HD_ 64

typedef _Float16  f16;
typedef __attribute__((ext_vector_type(8))) _Float16 f16x8;
typedef __attribute__((ext_vector_type(4))) _Float16 f16x4;
typedef __attribute__((ext_vector_type(4))) float    f32x4;

#define LOG2E 1.4426950408889634f
#define L2_10000_DIV32 0.41524101186092029f  /* log2(10000)/32 */
#define MASKVAL (-1.0e30f)

// NaN -> finite sanitizer (diagnostic guarantee: output always finite).
__device__ __forceinline__ float fin(float v) { return (v == v) ? v : 0.0f; }

__device__ __forceinline__ f16x8 cvt8(const float* p) {
  float4 a = *(const float4*)p;
  float4 b = *(const float4*)(p + 4);
  f16x8 h;
  h[0] = (f16)a.x; h[1] = (f16)a.y; h[2] = (f16)a.z; h[3] = (f16)a.w;
  h[4] = (f16)b.x; h[5] = (f16)b.y; h[6] = (f16)b.z; h[7] = (f16)b.w;
  return h;
}

// ---------------------------------------------------------------------------
// Kernel 1: qkv = x @ w_qkv^T (f16 MFMA, fp32 inputs converted in staging),
// fused RoPE epilogue.
//   x: [4096][1024] fp32   w_qkv: [3072][1024] fp32 (row e = output col)
//   Writes: Qb,Kb (B,H,S,HD) f16 (rope applied), Vt (B,H,HD,S) f16.
// 128x128 tile, BK=64, 4 waves 2x2, each wave 4x4 MFMA 16x16x32 tiles.
// ---------------------------------------------------------------------------
__global__ void __launch_bounds__(256)
k_qkv_rope(const float* __restrict__ x, const float* __restrict__ wqkv,
           f16* __restrict__ Qb, f16* __restrict__ Kb, f16* __restrict__ Vt)
{
  __shared__ __align__(16) f16 As[128 * 64];
  __shared__ __align__(16) f16 Bs[128 * 64];
  const int t = threadIdx.x;
  const int w = t >> 6;
  const int lane = t & 63;
  const int ll = lane & 15;      // A-row / B-col / C-col index
  const int quad = lane >> 4;    // k-chunk for A/B frags; row-quad for C/D
  const int wm = w >> 1, wn = w & 1;
  const int row0 = blockIdx.y * 128;
  const int col0 = blockIdx.x * 128;

  const f32x4 fz = {0.f, 0.f, 0.f, 0.f};
  f32x4 acc[4][4];
#pragma unroll
  for (int i = 0; i < 4; ++i)
#pragma unroll
    for (int j = 0; j < 4; ++j) acc[i][j] = fz;

  const int ldr = t >> 3;        // 0..31
  const int ldk = (t & 7) * 8;   // 0,8,..,56
  const float* ga = x    + (size_t)(row0 + ldr) * D_ + ldk;
  const float* gb = wqkv + (size_t)(col0 + ldr) * D_ + ldk;

  for (int kt = 0; kt < D_; kt += 64) {
    f16x8 ra[4], rb[4];
#pragma unroll
    for (int i = 0; i < 4; ++i) {
      ra[i] = cvt8(ga + (size_t)i * 32 * D_ + kt);
      rb[i] = cvt8(gb + (size_t)i * 32 * D_ + kt);
    }
    __syncthreads();   // previous iteration's LDS reads complete
#pragma unroll
    for (int i = 0; i < 4; ++i) {
      *(f16x8*)&As[(i * 32 + ldr) * 64 + ldk] = ra[i];
      *(f16x8*)&Bs[(i * 32 + ldr) * 64 + ldk] = rb[i];
    }
    __syncthreads();   // publish tile
#pragma unroll
    for (int kk = 0; kk < 64; kk += 32) {
      f16x8 a[4], b[4];
#pragma unroll
      for (int mt = 0; mt < 4; ++mt)
        a[mt] = *(const f16x8*)&As[(wm * 64 + mt * 16 + ll) * 64 + kk + quad * 8];
#pragma unroll
      for (int nt = 0; nt < 4; ++nt)
        b[nt] = *(const f16x8*)&Bs[(wn * 64 + nt * 16 + ll) * 64 + kk + quad * 8];
#pragma unroll
      for (int mt = 0; mt < 4; ++mt)
#pragma unroll
        for (int nt = 0; nt < 4; ++nt)
          acc[mt][nt] = __builtin_amdgcn_mfma_f32_16x16x32_f16(
              a[mt], b[nt], acc[mt][nt], 0, 0, 0);
    }
  }

  // Epilogue. C/D layout: col = ll (N), row = quad*4 + r (M).
  const int h3 = (col0 >> 6) + wn;   // 0..47; wave spans exactly one head
  if (h3 < 32) {
    f16* dst = (h3 < 16) ? Qb : Kb;
    const int h = (h3 < 16) ? h3 : h3 - 16;
    const float th0 = exp2f(-(float)ll * L2_10000_DIV32);        // dims ll, ll+32
    const float th1 = exp2f(-(float)(16 + ll) * L2_10000_DIV32); // dims 16+ll, 48+ll
#pragma unroll
    for (int mt = 0; mt < 4; ++mt) {
#pragma unroll
      for (int r = 0; r < 4; ++r) {
        const int row = row0 + wm * 64 + mt * 16 + quad * 4 + r;
        const int b = row >> 11;
        const int p = row & (S_ - 1);
        f16* base = dst + ((size_t)(b * H_ + h) * S_ + p) * HD_;
        const float fp = (float)p;
        float s0, c0, s1, c1;
        sincosf(fp * th0, &s0, &c0);
        sincosf(fp * th1, &s1, &c1);
        {
          float x1 = acc[mt][0][r], x2 = acc[mt][2][r];
          base[ll]      = (f16)fin(x1 * c0 - x2 * s0);
          base[ll + 32] = (f16)fin(x2 * c0 + x1 * s0);
        }
        {
          float x1 = acc[mt][1][r], x2 = acc[mt][3][r];
          base[16 + ll]      = (f16)fin(x1 * c1 - x2 * s1);
          base[16 + ll + 32] = (f16)fin(x2 * c1 + x1 * s1);
        }
      }
    }
  } else {
    const int hv = h3 - 32;  // V: store transposed (B,H,HD,S)
#pragma unroll
    for (int mt = 0; mt < 4; ++mt)
#pragma unroll
      for (int nt = 0; nt < 4; ++nt)
#pragma unroll
        for (int r = 0; r < 4; ++r) {
          const int row = row0 + wm * 64 + mt * 16 + quad * 4 + r;
          const int b = row >> 11;
          const int p = row & (S_ - 1);
          const int dd = nt * 16 + ll;
          Vt[((size_t)(b * H_ + hv) * HD_ + dd) * S_ + p] = (f16)fin(acc[mt][nt][r]);
        }
  }
}

// ---------------------------------------------------------------------------
// Kernel 2: causal flash attention (f16 MFMA). One block = 64 q-rows of one
// (b,h). 4 waves, 16 q-rows each. K/V tiles of 64. Online softmax; P goes
// through LDS to become the PV MFMA's A-operand. OutT = f16 (ws) or float
// (write O straight into d_out for the small-ws fallback).
// ---------------------------------------------------------------------------
template <typename OutT>
__global__ void __launch_bounds__(256)
k_attn(const f16* __restrict__ Qb, const f16* __restrict__ Kb,
       const f16* __restrict__ Vt, OutT* __restrict__ Ob)
{
  __shared__ __align__(16) f16 Qs[64 * 64];
  __shared__ __align__(16) f16 Ks[64 * 64];
  __shared__ __align__(16) f16 Vs[64 * 64];  // Vs[dd][kpos]
  __shared__ __align__(16) f16 Ps[64 * 64];  // per-wave 16-row slices
  const int t = threadIdx.x;
  const int w = t >> 6;
  const int lane = t & 63;
  const int ll = lane & 15;
  const int quad = lane >> 4;
  const int qt = blockIdx.x;
  const int h  = blockIdx.y;
  const int b  = blockIdx.z;
  const int q0 = qt * 64;
  const size_t bh = (size_t)b * H_ + h;
  const f16* Qg = Qb + (bh * S_ + q0) * HD_;
  const f16* Kg = Kb + bh * S_ * HD_;
  const f16* Vg = Vt + bh * HD_ * S_;
  const int ldr = t >> 3;
  const int ldc = (t & 7) * 8;

  // Stage Q once (published by the first in-loop barrier).
#pragma unroll
  for (int i = 0; i < 2; ++i) {
    f16x8 rq = *(const f16x8*)(Qg + (size_t)(i * 32 + ldr) * HD_ + ldc);
    *(f16x8*)&Qs[(i * 32 + ldr) * 64 + ldc] = rq;
  }

  const f32x4 fz = {0.f, 0.f, 0.f, 0.f};
  float mrun[4], lrun[4];
  f32x4 acco[4];
#pragma unroll
  for (int r = 0; r < 4; ++r) { mrun[r] = -1.0e4f; lrun[r] = 0.f; }
#pragma unroll
  for (int dt = 0; dt < 4; ++dt) acco[dt] = fz;

  f16* Pw = &Ps[w * 16 * 64];
  const int qrb = q0 + w * 16 + quad * 4;   // + r = this lane's q rows

  for (int kt = 0; kt <= qt; ++kt) {
    const int k0 = kt * 64;
    f16x8 rk[2], rv[2];
#pragma unroll
    for (int i = 0; i < 2; ++i) {
      rk[i] = *(const f16x8*)(Kg + (size_t)(k0 + i * 32 + ldr) * HD_ + ldc);
      rv[i] = *(const f16x8*)(Vg + (size_t)(i * 32 + ldr) * S_ + k0 + ldc);
    }
    __syncthreads();
#pragma unroll
    for (int i = 0; i < 2; ++i) {
      *(f16x8*)&Ks[(i * 32 + ldr) * 64 + ldc] = rk[i];
      *(f16x8*)&Vs[(i * 32 + ldr) * 64 + ldc] = rv[i];
    }
    __syncthreads();

    // S = Q K^T, this wave's 16 rows x 64 cols.
    f32x4 accs[4];
#pragma unroll
    for (int nt = 0; nt < 4; ++nt) accs[nt] = fz;
#pragma unroll
    for (int kk = 0; kk < 64; kk += 32) {
      f16x8 aq = *(const f16x8*)&Qs[(w * 16 + ll) * 64 + kk + quad * 8];
#pragma unroll
      for (int nt = 0; nt < 4; ++nt) {
        f16x8 bk = *(const f16x8*)&Ks[(nt * 16 + ll) * 64 + kk + quad * 8];
        accs[nt] = __builtin_amdgcn_mfma_f32_16x16x32_f16(aq, bk, accs[nt], 0, 0, 0);
      }
    }

    // Scale + causal mask + online softmax.
    float sc[4][4], pm[4];
#pragma unroll
    for (int r = 0; r < 4; ++r) pm[r] = MASKVAL;
    const bool diag = (kt == qt);
#pragma unroll
    for (int nt = 0; nt < 4; ++nt) {
      const int kcol = k0 + nt * 16 + ll;
#pragma unroll
      for (int r = 0; r < 4; ++r) {
        float s = accs[nt][r] * 0.125f;
        s = (s == s) ? s : MASKVAL;          // sanitize
        if (diag && kcol > qrb + r) s = MASKVAL;
        sc[nt][r] = s;
        pm[r] = fmaxf(pm[r], s);
      }
    }
#pragma unroll
    for (int off = 1; off < 16; off <<= 1)
#pragma unroll
      for (int r = 0; r < 4; ++r)
        pm[r] = fmaxf(pm[r], __shfl_xor(pm[r], off));

    float alpha[4];
#pragma unroll
    for (int r = 0; r < 4; ++r) {
      float mn = fmaxf(mrun[r], pm[r]);
      alpha[r] = exp2f((mrun[r] - mn) * LOG2E);
      mrun[r] = mn;
    }

    float ps[4] = {0.f, 0.f, 0.f, 0.f};
#pragma unroll
    for (int nt = 0; nt < 4; ++nt)
#pragma unroll
      for (int r = 0; r < 4; ++r) {
        float p = exp2f((sc[nt][r] - mrun[r]) * LOG2E);
        ps[r] += p;
        Pw[(quad * 4 + r) * 64 + nt * 16 + ll] = (f16)p;  // C-layout -> LDS
      }
#pragma unroll
    for (int off = 1; off < 16; off <<= 1)
#pragma unroll
      for (int r = 0; r < 4; ++r)
        ps[r] += __shfl_xor(ps[r], off);
#pragma unroll
    for (int r = 0; r < 4; ++r) lrun[r] = lrun[r] * alpha[r] + ps[r];
#pragma unroll
    for (int dt = 0; dt < 4; ++dt)
#pragma unroll
      for (int r = 0; r < 4; ++r) acco[dt][r] *= alpha[r];

    // O += P V  (A-operand from wave-private LDS slice).
#pragma unroll
    for (int kk = 0; kk < 64; kk += 32) {
      f16x8 ap = *(const f16x8*)&Pw[ll * 64 + kk + quad * 8];
#pragma unroll
      for (int dt = 0; dt < 4; ++dt) {
        f16x8 bv = *(const f16x8*)&Vs[(dt * 16 + ll) * 64 + kk + quad * 8];
        acco[dt] = __builtin_amdgcn_mfma_f32_16x16x32_f16(ap, bv, acco[dt], 0, 0, 0);
      }
    }
  }

  // Normalize; write O in (B,S,H*HD) layout.
  const size_t orow = (size_t)b * S_ + q0 + w * 16 + quad * 4;
#pragma unroll
  for (int r = 0; r < 4; ++r) {
    const float inv = 1.0f / fmaxf(lrun[r], 1e-30f);
#pragma unroll
    for (int dt = 0; dt < 4; ++dt)
      Ob[(orow + r) * D_ + h * HD_ + dt * 16 + ll] = (OutT)fin(acco[dt][r] * inv);
  }
}

// ---------------------------------------------------------------------------
// Kernel 3 (main): out = O @ w_out^T + b_out. A = Ob f16; B = w_out fp32
// converted to f16 during LDS staging. Output fp32.
// ---------------------------------------------------------------------------
__global__ void __launch_bounds__(256)
k_out_main(const f16* __restrict__ A, const float* __restrict__ W,
           const float* __restrict__ bias, float* __restrict__ out)
{
  __shared__ __align__(16) f16 As[128 * 64];
  __shared__ __align__(16) f16 Bs[128 * 64];
  const int t = threadIdx.x;
  const int w = t >> 6;
  const int lane = t & 63;
  const int ll = lane & 15;
  const int quad = lane >> 4;
  const int wm = w >> 1, wn = w & 1;
  const int row0 = blockIdx.y * 128;
  const int col0 = blockIdx.x * 128;

  const f32x4 fz = {0.f, 0.f, 0.f, 0.f};
  f32x4 acc[4][4];
#pragma unroll
  for (int i = 0; i < 4; ++i)
#pragma unroll
    for (int j = 0; j < 4; ++j) acc[i][j] = fz;

  const int ldr = t >> 3;
  const int ldk = (t & 7) * 8;
  const f16*   ga = A + (size_t)(row0 + ldr) * D_ + ldk;
  const float* gb = W + (size_t)(col0 + ldr) * D_ + ldk;

  for (int kt = 0; kt < D_; kt += 64) {
    f16x8 ra[4], rb[4];
#pragma unroll
    for (int i = 0; i < 4; ++i) {
      ra[i] = *(const f16x8*)(ga + (size_t)i * 32 * D_ + kt);
      rb[i] = cvt8(gb + (size_t)i * 32 * D_ + kt);
    }
    __syncthreads();
#pragma unroll
    for (int i = 0; i < 4; ++i) {
      *(f16x8*)&As[(i * 32 + ldr) * 64 + ldk] = ra[i];
      *(f16x8*)&Bs[(i * 32 + ldr) * 64 + ldk] = rb[i];
    }
    __syncthreads();
#pragma unroll
    for (int kk = 0; kk < 64; kk += 32) {
      f16x8 a[4], b[4];
#pragma unroll
      for (int mt = 0; mt < 4; ++mt)
        a[mt] = *(const f16x8*)&As[(wm * 64 + mt * 16 + ll) * 64 + kk + quad * 8];
#pragma unroll
      for (int nt = 0; nt < 4; ++nt)
        b[nt] = *(const f16x8*)&Bs[(wn * 64 + nt * 16 + ll) * 64 + kk + quad * 8];
#pragma unroll
      for (int mt = 0; mt < 4; ++mt)
#pragma unroll
        for (int nt = 0; nt < 4; ++nt)
          acc[mt][nt] = __builtin_amdgcn_mfma_f32_16x16x32_f16(
              a[mt], b[nt], acc[mt][nt], 0, 0, 0);
    }
  }

#pragma unroll
  for (int mt = 0; mt < 4; ++mt)
#pragma unroll
    for (int r = 0; r < 4; ++r) {
      const int row = row0 + wm * 64 + mt * 16 + quad * 4 + r;
#pragma unroll
      for (int nt = 0; nt < 4; ++nt) {
        const int col = col0 + wn * 64 + nt * 16 + ll;
        out[(size_t)row * D_ + col] = fin(acc[mt][nt][r] + bias[col]);
      }
    }
}

// ---------------------------------------------------------------------------
// Kernel 3 (fallback, small ws): in-place out-projection over d_out (fp32 O).
// Block = 16 rows; stage rows fp32->f16 into LDS; each wave computes 16-col
// tiles with B-fragments read directly from global w_out (fp32->f16).
// ---------------------------------------------------------------------------
__global__ void __launch_bounds__(256)
k_out_fb(const float* __restrict__ W, const float* __restrict__ bias,
         float* __restrict__ out)
{
  __shared__ __align__(16) f16 As[16 * 1024];
  const int t = threadIdx.x;
  const int w = t >> 6;
  const int lane = t & 63;
  const int ll = lane & 15;
  const int quad = lane >> 4;
  const int row0 = blockIdx.x * 16;

  for (int idx = t; idx < 4096; idx += 256) {
    const int rr = idx >> 8;            // 0..15
    const int c4 = (idx & 255) << 2;    // 0..1020
    float4 v = *(const float4*)&out[(size_t)(row0 + rr) * D_ + c4];
    f16x4 hh = {(f16)v.x, (f16)v.y, (f16)v.z, (f16)v.w};
    *(f16x4*)&As[rr * 1024 + c4] = hh;
  }
  __syncthreads();

  const f32x4 fz = {0.f, 0.f, 0.f, 0.f};
#pragma unroll 1
  for (int j = 0; j < 16; ++j) {
    const int nt = w * 16 + j;
    f32x4 acc = fz;
    for (int k0 = 0; k0 < D_; k0 += 32) {
      f16x8 aq = *(const f16x8*)&As[ll * 1024 + k0 + quad * 8];
      f16x8 bq = cvt8(&W[(size_t)(nt * 16 + ll) * D_ + k0 + quad * 8]);
      acc = __builtin_amdgcn_mfma_f32_16x16x32_f16(aq, bq, acc, 0, 0, 0);
    }
    const int col = nt * 16 + ll;
    const float bb = bias[col];
#pragma unroll
    for (int r = 0; r < 4; ++r)
      out[(size_t)(row0 + quad * 4 + r) * D_ + col] = fin(acc[r] + bb);
  }
}

// ---------------------------------------------------------------------------
extern "C" void kernel_launch(void* const* d_in, const int* in_sizes, int n_in,
                              void* d_out, int out_size, void* d_ws, size_t ws_size,
                              hipStream_t stream) {
  const float* x    = (const float*)d_in[0];
  const float* wqkv = (const float*)d_in[1];
  const float* wout = (const float*)d_in[2];
  const float* bout = (const float*)d_in[3];
  float* out = (float*)d_out;

  char* ws = (char*)d_ws;
  f16* Qb = (f16*)(ws);
  f16* Kb = (f16*)(ws + ((size_t)8  << 20));
  f16* Vt = (f16*)(ws + ((size_t)16 << 20));

  k_qkv_rope<<<dim3(3 * D_ / 128, (B_ * S_) / 128), 256, 0, stream>>>(
      x, wqkv, Qb, Kb, Vt);

  if (ws_size >= ((size_t)32 << 20)) {
    f16* Ob = (f16*)(ws + ((size_t)24 << 20));
    k_attn<f16><<<dim3(S_ / 64, H_, B_), 256, 0, stream>>>(Qb, Kb, Vt, Ob);
    k_out_main<<<dim3(D_ / 128, (B_ * S_) / 128), 256, 0, stream>>>(
        Ob, wout, bout, out);
  } else {
    k_attn<float><<<dim3(S_ / 64, H_, B_), 256, 0, stream>>>(Qb, Kb, Vt, out);
    k_out_fb<<<(B_ * S_) / 16, 256, 0, stream>>>(wout, bout, out);
  }
}

// Round 5
// 215.809 us; speedup vs baseline: 1.4449x; 1.4449x over previous
//
#include <hip/hip_runtime.h>
#include <hip/hip_fp16.h>
#include <math.h>

// Problem: B=2, S=2048, D=1024, H=16, HD=64, causal attention + RoPE.
// ALL inputs fp32 (reference dtypes), output fp32.
#define B_  2
#define S_  2048
#define D_  1024
#define H_  16
#define HD_ 64

typedef _Float16  f16;
typedef __attribute__((ext_vector_type(8))) _Float16 f16x8;
typedef __attribute__((ext_vector_type(4))) _Float16 f16x4;
typedef __attribute__((ext_vector_type(4))) float    f32x4;

#define LOG2E 1.4426950408889634f
#define L2_10000_DIV32 0.41524101186092029f  /* log2(10000)/32 */
#define PS 72   /* padded LDS row stride (f16) -> conflict-free b128 reads */

// NaN -> finite sanitizer (diagnostic guarantee: output always finite).
__device__ __forceinline__ float fin(float v) { return (v == v) ? v : 0.0f; }

__device__ __forceinline__ f16x8 cvt8(const float* p) {
  float4 a = *(const float4*)p;
  float4 b = *(const float4*)(p + 4);
  f16x8 h;
  h[0] = (f16)a.x; h[1] = (f16)a.y; h[2] = (f16)a.z; h[3] = (f16)a.w;
  h[4] = (f16)b.x; h[5] = (f16)b.y; h[6] = (f16)b.z; h[7] = (f16)b.w;
  return h;
}

// ---------------------------------------------------------------------------
// Kernel 1: qkv = x @ w_qkv^T (f16 MFMA, fp32 inputs converted in staging),
// fused RoPE epilogue. (unchanged from round 4 — verified)
// ---------------------------------------------------------------------------
__global__ void __launch_bounds__(256)
k_qkv_rope(const float* __restrict__ x, const float* __restrict__ wqkv,
           f16* __restrict__ Qb, f16* __restrict__ Kb, f16* __restrict__ Vt)
{
  __shared__ __align__(16) f16 As[128 * 64];
  __shared__ __align__(16) f16 Bs[128 * 64];
  const int t = threadIdx.x;
  const int w = t >> 6;
  const int lane = t & 63;
  const int ll = lane & 15;
  const int quad = lane >> 4;
  const int wm = w >> 1, wn = w & 1;
  const int row0 = blockIdx.y * 128;
  const int col0 = blockIdx.x * 128;

  const f32x4 fz = {0.f, 0.f, 0.f, 0.f};
  f32x4 acc[4][4];
#pragma unroll
  for (int i = 0; i < 4; ++i)
#pragma unroll
    for (int j = 0; j < 4; ++j) acc[i][j] = fz;

  const int ldr = t >> 3;
  const int ldk = (t & 7) * 8;
  const float* ga = x    + (size_t)(row0 + ldr) * D_ + ldk;
  const float* gb = wqkv + (size_t)(col0 + ldr) * D_ + ldk;

  for (int kt = 0; kt < D_; kt += 64) {
    f16x8 ra[4], rb[4];
#pragma unroll
    for (int i = 0; i < 4; ++i) {
      ra[i] = cvt8(ga + (size_t)i * 32 * D_ + kt);
      rb[i] = cvt8(gb + (size_t)i * 32 * D_ + kt);
    }
    __syncthreads();
#pragma unroll
    for (int i = 0; i < 4; ++i) {
      *(f16x8*)&As[(i * 32 + ldr) * 64 + ldk] = ra[i];
      *(f16x8*)&Bs[(i * 32 + ldr) * 64 + ldk] = rb[i];
    }
    __syncthreads();
#pragma unroll
    for (int kk = 0; kk < 64; kk += 32) {
      f16x8 a[4], b[4];
#pragma unroll
      for (int mt = 0; mt < 4; ++mt)
        a[mt] = *(const f16x8*)&As[(wm * 64 + mt * 16 + ll) * 64 + kk + quad * 8];
#pragma unroll
      for (int nt = 0; nt < 4; ++nt)
        b[nt] = *(const f16x8*)&Bs[(wn * 64 + nt * 16 + ll) * 64 + kk + quad * 8];
#pragma unroll
      for (int mt = 0; mt < 4; ++mt)
#pragma unroll
        for (int nt = 0; nt < 4; ++nt)
          acc[mt][nt] = __builtin_amdgcn_mfma_f32_16x16x32_f16(
              a[mt], b[nt], acc[mt][nt], 0, 0, 0);
    }
  }

  const int h3 = (col0 >> 6) + wn;
  if (h3 < 32) {
    f16* dst = (h3 < 16) ? Qb : Kb;
    const int h = (h3 < 16) ? h3 : h3 - 16;
    const float th0 = exp2f(-(float)ll * L2_10000_DIV32);
    const float th1 = exp2f(-(float)(16 + ll) * L2_10000_DIV32);
#pragma unroll
    for (int mt = 0; mt < 4; ++mt) {
#pragma unroll
      for (int r = 0; r < 4; ++r) {
        const int row = row0 + wm * 64 + mt * 16 + quad * 4 + r;
        const int b = row >> 11;
        const int p = row & (S_ - 1);
        f16* base = dst + ((size_t)(b * H_ + h) * S_ + p) * HD_;
        const float fp = (float)p;
        float s0, c0, s1, c1;
        sincosf(fp * th0, &s0, &c0);
        sincosf(fp * th1, &s1, &c1);
        {
          float x1 = acc[mt][0][r], x2 = acc[mt][2][r];
          base[ll]      = (f16)fin(x1 * c0 - x2 * s0);
          base[ll + 32] = (f16)fin(x2 * c0 + x1 * s0);
        }
        {
          float x1 = acc[mt][1][r], x2 = acc[mt][3][r];
          base[16 + ll]      = (f16)fin(x1 * c1 - x2 * s1);
          base[16 + ll + 32] = (f16)fin(x2 * c1 + x1 * s1);
        }
      }
    }
  } else {
    const int hv = h3 - 32;
#pragma unroll
    for (int mt = 0; mt < 4; ++mt)
#pragma unroll
      for (int nt = 0; nt < 4; ++nt)
#pragma unroll
        for (int r = 0; r < 4; ++r) {
          const int row = row0 + wm * 64 + mt * 16 + quad * 4 + r;
          const int b = row >> 11;
          const int p = row & (S_ - 1);
          const int dd = nt * 16 + ll;
          Vt[((size_t)(b * H_ + hv) * HD_ + dd) * S_ + p] = (f16)fin(acc[mt][nt][r]);
        }
  }
}

// ---------------------------------------------------------------------------
// k_attn2: causal flash attention, transposed formulation.
//   S^T = K·Q^T  (A = K rows, B = Q rows)  -> kcol lives in C regs
//   O^T = V^T·P^T (A = V^T rows from Vt, B = P^T rows = Pt[q][kcol] in LDS)
// Block = 4 waves; processes q-tiles qtA=blockIdx.x and qtB=31-qtA (balanced:
// 33 tile-computations each). K/V staged once per kt, shared by both tiles.
// Double-buffered K/V (1 barrier/iter), stride-72 LDS (conflict-free b128).
// Softmax per q=ll column: reductions = shfl_xor 16,32. P^T stored b64.
// ---------------------------------------------------------------------------
__device__ __forceinline__ void softmax_tile(
    f32x4 sc[4], bool diag, int qloc, int ll, int quad,
    float& mrun, float& lrun, float& alpha, f16* Pt)
{
  float pm = -3.0e4f;
#pragma unroll
  for (int nt = 0; nt < 4; ++nt)
#pragma unroll
    for (int r = 0; r < 4; ++r) {
      float s = sc[nt][r];
      s = (s == s) ? s : -3.0e4f;
      if (diag && (nt * 16 + quad * 4 + r) > qloc) s = -3.0e4f;
      sc[nt][r] = s;
      pm = fmaxf(pm, s);
    }
  pm = fmaxf(pm, __shfl_xor(pm, 16));
  pm = fmaxf(pm, __shfl_xor(pm, 32));
  const float mn = fmaxf(mrun, pm);
  alpha = exp2f(mrun - mn);
  mrun = mn;
  float ps = 0.f;
#pragma unroll
  for (int nt = 0; nt < 4; ++nt) {
    f16x4 pk;
#pragma unroll
    for (int r = 0; r < 4; ++r) {
      float p = exp2f(sc[nt][r] - mn);
      ps += p;
      pk[r] = (f16)p;
    }
    *(f16x4*)&Pt[ll * PS + nt * 16 + quad * 4] = pk;   // contiguous in kcol
  }
  ps += __shfl_xor(ps, 16);
  ps += __shfl_xor(ps, 32);
  lrun = lrun * alpha + ps;
}

__device__ __forceinline__ void write_o(
    f32x4 acco[4], float lrun, f16* Pt, int ll, int quad, int w,
    int qt, int b, int h, f16* __restrict__ Ob)
{
  const float inv = 1.0f / fmaxf(lrun, 1e-30f);
#pragma unroll
  for (int dg = 0; dg < 4; ++dg) {
    f16x4 ov;
#pragma unroll
    for (int r = 0; r < 4; ++r) ov[r] = (f16)fin(acco[dg][r] * inv);
    *(f16x4*)&Pt[ll * PS + dg * 16 + quad * 4] = ov;   // Os[q=ll][dd]
  }
#pragma unroll
  for (int s2 = 0; s2 < 2; ++s2) {
    f16x8 o = *(const f16x8*)&Pt[ll * PS + (quad + 4 * s2) * 8];
    const size_t row = (size_t)b * S_ + qt * 64 + w * 16 + ll;
    *(f16x8*)&Ob[row * D_ + h * HD_ + (quad + 4 * s2) * 8] = o;
  }
}

__global__ void __launch_bounds__(256, 2)
k_attn2(const f16* __restrict__ Qb, const f16* __restrict__ Kb,
        const f16* __restrict__ Vt, f16* __restrict__ Ob)
{
  __shared__ __align__(16) f16 Qs[128 * PS];      // 18.0 KB (A rows 0-63, B 64-127)
  __shared__ __align__(16) f16 Ks[2][64 * PS];    // 18.0 KB
  __shared__ __align__(16) f16 Vs[2][64 * PS];    // 18.0 KB
  __shared__ __align__(16) f16 Ps[4][16 * PS];    //  9.0 KB (per-wave P^T slice)

  const int t = threadIdx.x;
  const int w = t >> 6;
  const int lane = t & 63;
  const int ll = lane & 15;
  const int quad = lane >> 4;
  const int qtA = blockIdx.x;          // 0..15
  const int qtB = 31 - qtA;            // 16..31   (work = 33 tiles, uniform)
  const int h = blockIdx.y;
  const int b = blockIdx.z;
  const size_t bh = (size_t)b * H_ + h;
  const f16* Qg = Qb + bh * S_ * HD_;
  const f16* Kg = Kb + bh * S_ * HD_;
  const f16* Vg = Vt + bh * HD_ * S_;

  // ---- stage Q for both tiles, folding 0.125*log2(e) into Q ----
  {
    const int r = t >> 1;
    const int c0 = (t & 1) * 32;
    const int grow = (r < 64) ? (qtA * 64 + r) : (qtB * 64 + r - 64);
    const f16 hsc = (f16)(0.125f * LOG2E);
#pragma unroll
    for (int j = 0; j < 4; ++j) {
      f16x8 v = *(const f16x8*)(Qg + (size_t)grow * HD_ + c0 + j * 8);
#pragma unroll
      for (int e = 0; e < 8; ++e) v[e] *= hsc;
      *(f16x8*)&Qs[r * PS + c0 + j * 8] = v;
    }
  }
  // ---- stage K/V tile 0 -> buf 0 ----
  {
    const int r = t >> 2;
    const int c = (t & 3) * 16;
    f16x8 a0 = *(const f16x8*)(Kg + (size_t)r * HD_ + c);
    f16x8 a1 = *(const f16x8*)(Kg + (size_t)r * HD_ + c + 8);
    f16x8 b0 = *(const f16x8*)(Vg + (size_t)r * S_ + c);
    f16x8 b1 = *(const f16x8*)(Vg + (size_t)r * S_ + c + 8);
    *(f16x8*)&Ks[0][r * PS + c]     = a0;
    *(f16x8*)&Ks[0][r * PS + c + 8] = a1;
    *(f16x8*)&Vs[0][r * PS + c]     = b0;
    *(f16x8*)&Vs[0][r * PS + c + 8] = b1;
  }
  __syncthreads();

  const f32x4 fz = {0.f, 0.f, 0.f, 0.f};
  f32x4 accoA[4], accoB[4];
#pragma unroll
  for (int i = 0; i < 4; ++i) { accoA[i] = fz; accoB[i] = fz; }
  float mA = -3.0e4f, lA = 0.f, mB = -3.0e4f, lB = 0.f;
  const int qloc = w * 16 + ll;
  f16* Pt = &Ps[w][0];

  for (int kt = 0; kt <= qtB; ++kt) {
    const int cur = kt & 1;
    const bool pre = (kt < qtB);
    const int sr = t >> 2, scc = (t & 3) * 16;
    f16x8 nk0, nk1, nv0, nv1;
    if (pre) {  // prefetch next K/V tile into regs (latency hidden by compute)
      const int kn = (kt + 1) * 64;
      nk0 = *(const f16x8*)(Kg + (size_t)(kn + sr) * HD_ + scc);
      nk1 = *(const f16x8*)(Kg + (size_t)(kn + sr) * HD_ + scc + 8);
      nv0 = *(const f16x8*)(Vg + (size_t)sr * S_ + kn + scc);
      nv1 = *(const f16x8*)(Vg + (size_t)sr * S_ + kn + scc + 8);
    }
    const f16* Kc = Ks[cur];
    const f16* Vc = Vs[cur];
    const bool doA = (kt <= qtA);

    // K A-frags (shared by both tiles)
    f16x8 ak[2][4];
#pragma unroll
    for (int k2 = 0; k2 < 2; ++k2)
#pragma unroll
      for (int nt = 0; nt < 4; ++nt)
        ak[k2][nt] = *(const f16x8*)&Kc[(nt * 16 + ll) * PS + k2 * 32 + quad * 8];

    // S^T = K·Q^T for tile B (always) and tile A (while active)
    f32x4 sB[4] = {fz, fz, fz, fz};
#pragma unroll
    for (int k2 = 0; k2 < 2; ++k2) {
      f16x8 bq = *(const f16x8*)&Qs[(64 + w * 16 + ll) * PS + k2 * 32 + quad * 8];
#pragma unroll
      for (int nt = 0; nt < 4; ++nt)
        sB[nt] = __builtin_amdgcn_mfma_f32_16x16x32_f16(ak[k2][nt], bq, sB[nt], 0, 0, 0);
    }
    f32x4 sA[4] = {fz, fz, fz, fz};
    if (doA) {
#pragma unroll
      for (int k2 = 0; k2 < 2; ++k2) {
        f16x8 bq = *(const f16x8*)&Qs[(w * 16 + ll) * PS + k2 * 32 + quad * 8];
#pragma unroll
        for (int nt = 0; nt < 4; ++nt)
          sA[nt] = __builtin_amdgcn_mfma_f32_16x16x32_f16(ak[k2][nt], bq, sA[nt], 0, 0, 0);
      }
    }

    // V A-frags (shared by both tiles)
    f16x8 av[2][4];
#pragma unroll
    for (int k2 = 0; k2 < 2; ++k2)
#pragma unroll
      for (int dg = 0; dg < 4; ++dg)
        av[k2][dg] = *(const f16x8*)&Vc[(dg * 16 + ll) * PS + k2 * 32 + quad * 8];

    float alpha;
    if (doA) {  // tile A: softmax -> Pt, rescale, O^T += V^T P^T
      softmax_tile(sA, kt == qtA, qloc, ll, quad, mA, lA, alpha, Pt);
#pragma unroll
      for (int dg = 0; dg < 4; ++dg)
#pragma unroll
        for (int r = 0; r < 4; ++r) accoA[dg][r] *= alpha;
#pragma unroll
      for (int k2 = 0; k2 < 2; ++k2) {
        f16x8 bp = *(const f16x8*)&Pt[ll * PS + k2 * 32 + quad * 8];
#pragma unroll
        for (int dg = 0; dg < 4; ++dg)
          accoA[dg] = __builtin_amdgcn_mfma_f32_16x16x32_f16(av[k2][dg], bp, accoA[dg], 0, 0, 0);
      }
    }
    {   // tile B (Pt reused; same-wave DS ops are in-order)
      softmax_tile(sB, kt == qtB, qloc, ll, quad, mB, lB, alpha, Pt);
#pragma unroll
      for (int dg = 0; dg < 4; ++dg)
#pragma unroll
        for (int r = 0; r < 4; ++r) accoB[dg][r] *= alpha;
#pragma unroll
      for (int k2 = 0; k2 < 2; ++k2) {
        f16x8 bp = *(const f16x8*)&Pt[ll * PS + k2 * 32 + quad * 8];
#pragma unroll
        for (int dg = 0; dg < 4; ++dg)
          accoB[dg] = __builtin_amdgcn_mfma_f32_16x16x32_f16(av[k2][dg], bp, accoB[dg], 0, 0, 0);
      }
    }

    if (pre) {  // publish next tile into the other buffer
      *(f16x8*)&Ks[1 - cur][sr * PS + scc]     = nk0;
      *(f16x8*)&Ks[1 - cur][sr * PS + scc + 8] = nk1;
      *(f16x8*)&Vs[1 - cur][sr * PS + scc]     = nv0;
      *(f16x8*)&Vs[1 - cur][sr * PS + scc + 8] = nv1;
    }
    __syncthreads();
  }

  // Epilogue: O^T -> (transpose via Pt) -> Ob[B*S][D] f16
  write_o(accoA, lA, Pt, ll, quad, w, qtA, b, h, Ob);
  write_o(accoB, lB, Pt, ll, quad, w, qtB, b, h, Ob);
}

// ---------------------------------------------------------------------------
// Kernel 3: out = O @ w_out^T + b_out. (unchanged from round 4 — verified)
// ---------------------------------------------------------------------------
__global__ void __launch_bounds__(256)
k_out_main(const f16* __restrict__ A, const float* __restrict__ W,
           const float* __restrict__ bias, float* __restrict__ out)
{
  __shared__ __align__(16) f16 As[128 * 64];
  __shared__ __align__(16) f16 Bs[128 * 64];
  const int t = threadIdx.x;
  const int w = t >> 6;
  const int lane = t & 63;
  const int ll = lane & 15;
  const int quad = lane >> 4;
  const int wm = w >> 1, wn = w & 1;
  const int row0 = blockIdx.y * 128;
  const int col0 = blockIdx.x * 128;

  const f32x4 fz = {0.f, 0.f, 0.f, 0.f};
  f32x4 acc[4][4];
#pragma unroll
  for (int i = 0; i < 4; ++i)
#pragma unroll
    for (int j = 0; j < 4; ++j) acc[i][j] = fz;

  const int ldr = t >> 3;
  const int ldk = (t & 7) * 8;
  const f16*   ga = A + (size_t)(row0 + ldr) * D_ + ldk;
  const float* gb = W + (size_t)(col0 + ldr) * D_ + ldk;

  for (int kt = 0; kt < D_; kt += 64) {
    f16x8 ra[4], rb[4];
#pragma unroll
    for (int i = 0; i < 4; ++i) {
      ra[i] = *(const f16x8*)(ga + (size_t)i * 32 * D_ + kt);
      rb[i] = cvt8(gb + (size_t)i * 32 * D_ + kt);
    }
    __syncthreads();
#pragma unroll
    for (int i = 0; i < 4; ++i) {
      *(f16x8*)&As[(i * 32 + ldr) * 64 + ldk] = ra[i];
      *(f16x8*)&Bs[(i * 32 + ldr) * 64 + ldk] = rb[i];
    }
    __syncthreads();
#pragma unroll
    for (int kk = 0; kk < 64; kk += 32) {
      f16x8 a[4], b[4];
#pragma unroll
      for (int mt = 0; mt < 4; ++mt)
        a[mt] = *(const f16x8*)&As[(wm * 64 + mt * 16 + ll) * 64 + kk + quad * 8];
#pragma unroll
      for (int nt = 0; nt < 4; ++nt)
        b[nt] = *(const f16x8*)&Bs[(wn * 64 + nt * 16 + ll) * 64 + kk + quad * 8];
#pragma unroll
      for (int mt = 0; mt < 4; ++mt)
#pragma unroll
        for (int nt = 0; nt < 4; ++nt)
          acc[mt][nt] = __builtin_amdgcn_mfma_f32_16x16x32_f16(
              a[mt], b[nt], acc[mt][nt], 0, 0, 0);
    }
  }

#pragma unroll
  for (int mt = 0; mt < 4; ++mt)
#pragma unroll
    for (int r = 0; r < 4; ++r) {
      const int row = row0 + wm * 64 + mt * 16 + quad * 4 + r;
#pragma unroll
      for (int nt = 0; nt < 4; ++nt) {
        const int col = col0 + wn * 64 + nt * 16 + ll;
        out[(size_t)row * D_ + col] = fin(acc[mt][nt][r] + bias[col]);
      }
    }
}

// ---------------------------------------------------------------------------
extern "C" void kernel_launch(void* const* d_in, const int* in_sizes, int n_in,
                              void* d_out, int out_size, void* d_ws, size_t ws_size,
                              hipStream_t stream) {
  const float* x    = (const float*)d_in[0];
  const float* wqkv = (const float*)d_in[1];
  const float* wout = (const float*)d_in[2];
  const float* bout = (const float*)d_in[3];
  float* out = (float*)d_out;

  char* ws = (char*)d_ws;
  f16* Qb = (f16*)(ws);
  f16* Kb = (f16*)(ws + ((size_t)8  << 20));
  f16* Vt = (f16*)(ws + ((size_t)16 << 20));
  f16* Ob = (f16*)(ws + ((size_t)24 << 20));

  k_qkv_rope<<<dim3(3 * D_ / 128, (B_ * S_) / 128), 256, 0, stream>>>(
      x, wqkv, Qb, Kb, Vt);
  k_attn2<<<dim3(16, H_, B_), 256, 0, stream>>>(Qb, Kb, Vt, Ob);
  k_out_main<<<dim3(D_ / 128, (B_ * S_) / 128), 256, 0, stream>>>(
      Ob, wout, bout, out);
}